// Round 11
// baseline (14344.809 us; speedup 1.0000x reference)
//
#include <hip/hip_runtime.h>

// ---------------------------------------------------------------------------
// SequencePredictorRecurrentTransformer on MI355X (gfx950)
//
// I/O: fp32 (x int32). Internal: bf16 storage, fp32 accumulation.
// Layout [b][t][d] bt-major. Batch groups of Bg sized to ws_size.
//
// Round-23: OCCUPANCY 1 -> 2 blocks/CU in gemm_p8 via BK 64->32 (LDS
// 128->64 KiB), __launch_bounds__(512,4). Mechanism (m114): independent
// co-resident blocks overlap each other's barrier/wait stalls; r19-r22
// showed the 1-block/CU lockstep schedule is stall-bound (MfmaUtil ~28%,
// Occupancy ~21%) and insensitive to schedule-level changes.
// Same 256^2 tile (49MB fetch kept), GM-grouped order, de-pinned 2-phase
// skeleton. BK=32 ledger (4 loads/thread/K-tile, FIFO-traced):
//   prologue: A0,B0,B1 (6 loads), vmcnt(2) [A0,B0 landed, B1 in flight]
//   phA(t): read A-q0 + B; stage A(t+1) -> OTHER buf (last reader closed
//           at phB(t-1) end barrier); 8 MFMA
//   phB(t): read A-q1; stage B(t+2) -> THIS buf (B(t) last read phA(t));
//           8 MFMA; vmcnt(2) retires {B(t+1),A(t+1)}, keeps B(t+2)
// Rows now 64B: granule mask 7->3, offsets r*64. Frag/epilogue unchanged.
// Non-GEMM kernels identical to round-22 (1501.2us passing).
// ---------------------------------------------------------------------------

typedef unsigned short u16;
typedef __bf16 bf16x8 __attribute__((ext_vector_type(8)));
typedef float f32x4 __attribute__((ext_vector_type(4)));
typedef float f32x16 __attribute__((ext_vector_type(16)));

#define T_SEQ 2048
#define BATCH 32
#define NHEADS 8
#define CT 64
#define NCHUNK 32             // T/CT

// skewed column offset for transposed LDS arrays (row r, t-index k)
#define SKEW(r, k) ((((k) + (((r) >> 3) << 3))) & 63)

__device__ __forceinline__ float b2f(u16 u) {
    union { unsigned int i; float f; } v; v.i = ((unsigned int)u) << 16; return v.f;
}
__device__ __forceinline__ u16 f2b(float f) {
    union { __bf16 b; u16 u; } v; v.b = (__bf16)f; return v.u;   // HW cvt, RNE
}

__device__ __forceinline__ void gl_lds16(const u16* g, u16* l) {
    __builtin_amdgcn_global_load_lds(
        (const __attribute__((address_space(1))) void*)g,
        (__attribute__((address_space(3))) void*)l,
        16, 0, 0);
}

// compiler-only memory fence (no hardware wait)
#define CFENCE() asm volatile("" ::: "memory")

// ---------------------------------------------------------------------------
// 256^2 2-phase GEMM, BK=32: C[M,N] = act(A@BT^T + bias [+ R]), bf16.
// M,N multiples of 256; K multiple of 32, K>=128. grid = (M/256)*nbn,
// nbn = N/256, M/256 a multiple of GM. ACT: 0=none, 1=relu, 2=phi(elu+1)
// where col < act_split. Block order: GM bm-tiles per group, bn sweep.
// ---------------------------------------------------------------------------
template<int ACT, bool RES>
__global__ __launch_bounds__(512, 4) void gemm_p8(
    const u16* __restrict__ A, const u16* __restrict__ BT,
    const float* __restrict__ bias, const u16* __restrict__ R,
    u16* __restrict__ C,
    int M, int N, int K, int act_split, int nbn, int GM)
{
    __shared__ __align__(16) u16 AsS[2][256 * 32];
    __shared__ __align__(16) u16 BsS[2][256 * 32];

    // grouped ordering (gemm_mx-verified): GM bm-tiles per group, bn sweep
    const int bid = blockIdx.x;
    const int gsz = GM * nbn;
    const int grp = bid / gsz, rm = bid % gsz;
    const int bm = (grp * GM + rm % GM) * 256;
    const int bn = (rm / GM) * 256;
    if (bm >= M || bn >= N) return;           // guard (block-uniform)

    const int tid = threadIdx.x;
    const int lane = tid & 63;
    const int w  = tid >> 6;      // 0..7
    const int wr = w >> 2;        // 0..1 : M half (128 rows)
    const int wc = w & 3;         // 0..3 : N quarter (64 cols)
    const int l32 = lane & 31;
    const int kh  = lane >> 5;    // k-half selector for 32x32x16

    const int NT = K >> 5;        // K-tiles of 32

    // --- staging: pass i in {0,1}: dest elem (i*4096 + tid*8), covering
    //     row = i*128 + tid/4, granule slot = tid&3; source granule
    //     pre-swizzled gs = (tid&3) ^ (row&3) (involution, rule #21) ---
    const u16* pA[2]; const u16* pB[2];
    #pragma unroll
    for (int i = 0; i < 2; i++) {
        const int row = i * 128 + (tid >> 2);
        const int gs = (tid & 3) ^ (row & 3);
        pA[i] = A  + (size_t)(bm + row) * K + gs * 8;
        pB[i] = BT + (size_t)(bn + row) * K + gs * 8;
    }

    // --- hoisted LDS read byte-offsets (row stride 64B, granule mask 3) ---
    int offA[2][2][2], offB[2][2];
    #pragma unroll
    for (int h = 0; h < 2; h++)
        #pragma unroll
        for (int mf = 0; mf < 2; mf++) {
            const int r = wr * 128 + h * 64 + mf * 32 + l32;
            #pragma unroll
            for (int ks = 0; ks < 2; ks++)
                offA[h][mf][ks] = r * 64 + (((ks * 2 + kh) ^ (r & 3)) * 16);
        }
    #pragma unroll
    for (int jb = 0; jb < 2; jb++) {
        const int rb = wc * 64 + jb * 32 + l32;
        #pragma unroll
        for (int ks = 0; ks < 2; ks++)
            offB[jb][ks] = rb * 64 + (((ks * 2 + kh) ^ (rb & 3)) * 16);
    }

    f32x16 acc[4][2] = {};

    // stage pass i of a 256x32 tile at k-offset k0 (elements)
    auto stage = [&](u16* lds, const u16* p, int i, int k0) {
        gl_lds16(p + k0, lds + i * 4096 + w * 512);
    };

    // ---- prologue: A0, B0 (tile 0), B1 (tile 1) = 6 loads ----
    stage(AsS[0], pA[0], 0, 0); stage(AsS[0], pA[1], 1, 0);
    stage(BsS[0], pB[0], 0, 0); stage(BsS[0], pB[1], 1, 0);
    stage(BsS[1], pB[0], 0, 32); stage(BsS[1], pB[1], 1, 32);
    asm volatile("s_waitcnt vmcnt(2)" ::: "memory");   // A0,B0 landed
    __builtin_amdgcn_s_barrier();

    bf16x8 af[2][2], b0[2], b1[2];

    for (int t = 0; t < NT; ++t) {
        u16* As_ = AsS[t & 1];
        u16* Bs_ = BsS[t & 1];
        u16* An1 = AsS[(t + 1) & 1];          // other buffer (A slot free)
        const int k1 = (t + 1) << 5;
        const int k2 = (t + 2) << 5;
        const bool pf1 = (t + 1) < NT;
        const bool pf2 = (t + 2) < NT;

        // ===== phase A: read A-q0 + B(b0,b1); stage A(t+1) -> other buf ===
        #pragma unroll
        for (int mf = 0; mf < 2; mf++)
            #pragma unroll
            for (int ks = 0; ks < 2; ks++)
                af[mf][ks] = *(const bf16x8*)((const char*)As_ + offA[0][mf][ks]);
        #pragma unroll
        for (int ks = 0; ks < 2; ks++) {
            b0[ks] = *(const bf16x8*)((const char*)Bs_ + offB[0][ks]);
            b1[ks] = *(const bf16x8*)((const char*)Bs_ + offB[1][ks]);
        }
        if (pf1) { stage(An1, pA[0], 0, k1); stage(An1, pA[1], 1, k1); }
        CFENCE();
        __builtin_amdgcn_s_barrier();
        CFENCE();
        #pragma unroll
        for (int ks = 0; ks < 2; ks++)
            #pragma unroll
            for (int mf = 0; mf < 2; mf++) {
                acc[mf][0] = __builtin_amdgcn_mfma_f32_32x32x16_bf16(
                    af[mf][ks], b0[ks], acc[mf][0], 0, 0, 0);
                acc[mf][1] = __builtin_amdgcn_mfma_f32_32x32x16_bf16(
                    af[mf][ks], b1[ks], acc[mf][1], 0, 0, 0);
            }
        CFENCE();
        __builtin_amdgcn_s_barrier();
        CFENCE();

        // ===== phase B: read A-q1; stage B(t+2) -> this buf (B(t) dead) ===
        #pragma unroll
        for (int mf = 0; mf < 2; mf++)
            #pragma unroll
            for (int ks = 0; ks < 2; ks++)
                af[mf][ks] = *(const bf16x8*)((const char*)As_ + offA[1][mf][ks]);
        if (pf2) { stage(Bs_, pB[0], 0, k2); stage(Bs_, pB[1], 1, k2); }
        CFENCE();
        __builtin_amdgcn_s_barrier();
        CFENCE();
        #pragma unroll
        for (int ks = 0; ks < 2; ks++)
            #pragma unroll
            for (int mf = 0; mf < 2; mf++) {
                acc[2 + mf][0] = __builtin_amdgcn_mfma_f32_32x32x16_bf16(
                    af[mf][ks], b0[ks], acc[2 + mf][0], 0, 0, 0);
                acc[2 + mf][1] = __builtin_amdgcn_mfma_f32_32x32x16_bf16(
                    af[mf][ks], b1[ks], acc[2 + mf][1], 0, 0, 0);
            }
        // retire {B(t+1), A(t+1)}; keep B(t+2)'s 2 loads in flight
        if (pf2) asm volatile("s_waitcnt vmcnt(2)" ::: "memory");
        else     asm volatile("s_waitcnt vmcnt(0)" ::: "memory");
        __builtin_amdgcn_s_barrier();
        CFENCE();
    }

    // Epilogue. D (m74/m101): col = lane&31, row = (reg&3)+8*(reg>>2)+4*kh.
    #pragma unroll
    for (int i = 0; i < 4; i++) {
        const int row0 = bm + wr * 128 + i * 32 + 4 * kh;
        #pragma unroll
        for (int j = 0; j < 2; j++) {
            const int col = bn + wc * 64 + j * 32 + l32;
            const float bb = bias[col];
            const bool phi = (ACT == 2) && (col < act_split);
            #pragma unroll
            for (int reg = 0; reg < 16; reg++) {
                const int m = row0 + (reg & 3) + 8 * (reg >> 2);
                float v = acc[i][j][reg] + bb;
                if (RES) v += b2f(R[(size_t)m * N + col]);
                if (ACT == 1) v = fmaxf(v, 0.f);
                if (ACT == 2) { if (phi) v = (v > 0.f) ? (v + 1.f) : __expf(v); }
                C[(size_t)m * N + col] = f2b(v);
            }
        }
    }
}

// ---------------------------------------------------------------------------
// Small-N GEMM (final projection, N=64): fp32 out, swapped epilogue (16B st).
// ---------------------------------------------------------------------------
template<int BM, int BN, int WM, int WN>
__global__ __launch_bounds__(WM*WN*64) void gemm_sm(
    const u16* __restrict__ A, const u16* __restrict__ BT,
    const float* __restrict__ bias, float* __restrict__ C,
    int M, int N, int K)
{
    constexpr int BK = 32;
    constexpr int LDT = BK + 8;
    constexpr int NTHR = WM * WN * 64;
    __shared__ __align__(16) u16 As[BM * LDT];
    __shared__ __align__(16) u16 Bs[BN * LDT];

    const int tid = threadIdx.x;
    const int bm = blockIdx.y * BM;
    const int bn = blockIdx.x * BN;
    const int lane = tid & 63;
    const int wid = tid >> 6;
    const int wrow = (wid / WN) * (BM / WM);
    const int wcol = (wid % WN) * (BN / WN);
    constexpr int FM = BM / WM / 16;
    constexpr int FN = BN / WN / 16;
    const int lrow = lane & 15;
    const int lk = (lane >> 4) * 8;

    f32x4 acc[FM][FN] = {};

    for (int k0 = 0; k0 < K; k0 += BK) {
        #pragma unroll
        for (int g0 = 0; g0 < BM * 4; g0 += NTHR) {
            int g = g0 + tid;
            int row = g >> 2, kk = (g & 3) * 8;
            *(uint4*)&As[row * LDT + kk] =
                *(const uint4*)&A[(size_t)(bm + row) * K + k0 + kk];
        }
        #pragma unroll
        for (int g0 = 0; g0 < BN * 4; g0 += NTHR) {
            int g = g0 + tid;
            int row = g >> 2, kk = (g & 3) * 8;
            *(uint4*)&Bs[row * LDT + kk] =
                *(const uint4*)&BT[(size_t)(bn + row) * K + k0 + kk];
        }
        __syncthreads();
        bf16x8 af[FM], bfv[FN];
        #pragma unroll
        for (int i = 0; i < FM; i++)
            af[i] = *(const bf16x8*)&As[(wrow + i * 16 + lrow) * LDT + lk];
        #pragma unroll
        for (int j = 0; j < FN; j++)
            bfv[j] = *(const bf16x8*)&Bs[(wcol + j * 16 + lrow) * LDT + lk];
        #pragma unroll
        for (int i = 0; i < FM; i++)
            #pragma unroll
            for (int j = 0; j < FN; j++)
                acc[i][j] = __builtin_amdgcn_mfma_f32_16x16x32_bf16(
                    bfv[j], af[i], acc[i][j], 0, 0, 0);   // swapped
        __syncthreads();
    }

    #pragma unroll
    for (int i = 0; i < FM; i++) {
        const int row = bm + wrow + i * 16 + lrow;
        #pragma unroll
        for (int j = 0; j < FN; j++) {
            const int col0 = bn + wcol + j * 16 + (lane >> 4) * 4;
            const float4 bb = *(const float4*)&bias[col0];
            float4 o = { acc[i][j][0] + bb.x, acc[i][j][1] + bb.y,
                         acc[i][j][2] + bb.z, acc[i][j][3] + bb.w };
            *(float4*)&C[(size_t)row * N + col0] = o;
        }
    }
}

// ---------------------------------------------------------------------------
// Mega-preprocess: ALL weight transposes (fp32->bf16) + PE table + qkv bias
// concat in ONE dispatch. Block ranges (block-uniform branches).
// ---------------------------------------------------------------------------
__global__ __launch_bounds__(256) void prep_kernel(
    const float* __restrict__ Wq, const float* __restrict__ Wk,
    const float* __restrict__ Wv, const float* __restrict__ Wo,
    const float* __restrict__ W1, const float* __restrict__ W2,
    const float* __restrict__ Wp,
    const float* __restrict__ bq, const float* __restrict__ bk,
    const float* __restrict__ bv,
    u16* __restrict__ qkvT, u16* __restrict__ woT, u16* __restrict__ w1T,
    u16* __restrict__ w2T, u16* __restrict__ wpT, u16* __restrict__ pe,
    float* __restrict__ bqkv)
{
    __shared__ float tile[32][33];
    const int bid = blockIdx.x;
    const float* src; u16* dst; int K, N, bx, by;

    if (bid < 1536) {
        int l = bid / 768, r = bid % 768, m = r >> 8, t = r & 255;
        const float* s3[3] = { Wq, Wk, Wv };            // m block-uniform
        src = s3[m] + (size_t)l * 262144;
        dst = qkvT + (size_t)l * 786432 + (size_t)m * 262144;
        K = 512; N = 512; bx = t & 15; by = t >> 4;
    } else if (bid < 2048) {
        int r = bid - 1536, l = r >> 8, t = r & 255;
        src = Wo + (size_t)l * 262144; dst = woT + (size_t)l * 262144;
        K = 512; N = 512; bx = t & 15; by = t >> 4;
    } else if (bid < 4096) {
        int r = bid - 2048, l = r >> 10, t = r & 1023;
        src = W1 + (size_t)l * 1048576; dst = w1T + (size_t)l * 1048576;
        K = 512; N = 2048; bx = t & 63; by = t >> 6;
    } else if (bid < 6144) {
        int r = bid - 4096, l = r >> 10, t = r & 1023;
        src = W2 + (size_t)l * 1048576; dst = w2T + (size_t)l * 1048576;
        K = 2048; N = 512; bx = t & 15; by = t >> 4;
    } else if (bid < 6176) {
        int t = bid - 6144;
        src = Wp; dst = wpT; K = 512; N = 64; bx = t & 1; by = t >> 1;
    } else if (bid < 8224) {
        int id = (bid - 6176) * 256 + threadIdx.x;      // < 2048*256
        int t = id >> 8, j = id & 255;
        int i = j >> 1;
        float div = expf(-(float)(2 * i) * (9.210340371976184f / 256.f));
        float arg = (float)t * div;
        pe[id] = f2b((j & 1) ? cosf(arg) : sinf(arg));
        return;
    } else {
        int id = (bid - 8224) * 256 + threadIdx.x;
        if (id < 3072) {
            int l = id / 1536, i2 = id % 1536;
            float v = (i2 < 512) ? bq[l * 512 + i2]
                    : (i2 < 1024) ? bk[l * 512 + i2 - 512]
                                  : bv[l * 512 + i2 - 1024];
            bqkv[id] = v;
        }
        return;
    }

    // 32x32 transpose tile: dst[N][K] = bf16(src[K][N])
    int tx = threadIdx.x & 31, ty = threadIdx.x >> 5;
    #pragma unroll
    for (int yy = 0; yy < 4; yy++) {
        int k = by * 32 + ty + yy * 8;
        tile[ty + yy * 8][tx] = src[(size_t)k * N + bx * 32 + tx];
    }
    __syncthreads();
    #pragma unroll
    for (int yy = 0; yy < 4; yy++) {
        int n = bx * 32 + ty + yy * 8;
        dst[(size_t)n * K + by * 32 + tx] = f2b(tile[tx][ty + yy * 8]);
    }
}

// ---------------------------------------------------------------------------
// Embedding (bt-major): gather from E and the PE table, 8 elems/thread.
// Grid = rows/4 blocks of 256 threads (2048 u16 per block).
// ---------------------------------------------------------------------------
__global__ __launch_bounds__(256) void embed_kernel(
    const int* __restrict__ x, const float* __restrict__ E,
    const u16* __restrict__ pe, u16* __restrict__ h, int b0)
{
    int idx = blockIdx.x * 256 + threadIdx.x;   // 8-elem granule id
    int e8 = idx * 8;
    int r = e8 >> 9;          // global row
    int c = e8 & 511;         // col base (multiple of 8)
    int t = r & (T_SEQ - 1);
    int b = b0 + (r >> 11);
    union { u16 u[8]; uint4 v; } o;
    if (c < 256) {
        const float* Ep = &E[(size_t)x[t * BATCH + b] * 256 + c];
        #pragma unroll
        for (int i = 0; i < 8; i++) o.u[i] = f2b(Ep[i]);
    } else {
        o.v = *(const uint4*)&pe[t * 256 + (c - 256)];
    }
    *(uint4*)&h[e8] = o.v;
}

// ---------------------------------------------------------------------------
// Phase A (MFMA): S'_c[m][d] = sum_t V[t][m]*K[t][d] -> bf16; Z_c[d]=sum K.
// Loader: uint4 global; skewed transposed LDS stores (static reg indexing).
// ---------------------------------------------------------------------------
__global__ __launch_bounds__(256) void attn_chunk_sums(
    const u16* __restrict__ qkv, u16* __restrict__ S, float* __restrict__ Z,
    int BHg)
{
    __shared__ __align__(16) u16 Kt[64 * 72], Vt[64 * 72];   // skewed [d][t]
    int bid = blockIdx.x;
    int bh = bid % BHg, c = bid / BHg;
    int bl = bh >> 3, hh = bh & 7;
    {
        const int m  = threadIdx.x & 7;
        const int d0 = m * 8;
        #pragma unroll
        for (int p = 0; p < 2; p++) {
            const int t = p * 32 + (threadIdx.x >> 3);
            size_t rr = ((size_t)(bl * T_SEQ + c * 64 + t)) * 1536 + hh * 64 + d0;
            uint4 kv = *(const uint4*)&qkv[rr + 512];
            uint4 vv = *(const uint4*)&qkv[rr + 1024];
            const u16* kp = (const u16*)&kv;
            const u16* vp = (const u16*)&vv;
            const int sk = (t + d0) & 63;         // skew col for rows d0..d0+7
            u16* kb = &Kt[d0 * 72 + sk];
            u16* vb = &Vt[d0 * 72 + sk];
            #pragma unroll
            for (int s = 0; s < 8; s++) { kb[s * 72] = kp[s]; vb[s * 72] = vp[s]; }
        }
    }
    __syncthreads();
    int lane = threadIdx.x & 63;
    int w = threadIdx.x >> 6;
    int lrow = lane & 15, quad = lane >> 4;
    int m0 = w * 16;
    f32x4 acc[4] = {};
    #pragma unroll
    for (int k0 = 0; k0 < 64; k0 += 32) {
        const int ra = m0 + lrow;
        bf16x8 af = *(const bf16x8*)&Vt[ra * 72 + SKEW(ra, k0 + quad * 8)];
        #pragma unroll
        for (int jt = 0; jt < 4; jt++) {
            const int rb = jt * 16 + lrow;
            bf16x8 bf = *(const bf16x8*)&Kt[rb * 72 + SKEW(rb, k0 + quad * 8)];
            acc[jt] = __builtin_amdgcn_mfma_f32_16x16x32_bf16(bf, af, acc[jt], 0, 0, 0);
        }
    }
    size_t base = ((size_t)c * BHg + bh) * 4096;
    const int m = m0 + lrow;
    #pragma unroll
    for (int jt = 0; jt < 4; jt++) {
        const int d0 = jt * 16 + quad * 4;
        union { u16 q[4]; uint2 u; } pk;
        #pragma unroll
        for (int r = 0; r < 4; r++) pk.q[r] = f2b(acc[jt][r]);
        *(uint2*)&S[base + m * 64 + d0] = pk.u;
    }
    if (threadIdx.x < 64) {
        const int d = threadIdx.x;
        float z = 0.f;
        #pragma unroll
        for (int t8 = 0; t8 < 64; t8 += 8) {
            bf16x8 kk = *(const bf16x8*)&Kt[d * 72 + SKEW(d, t8)];
            #pragma unroll
            for (int u = 0; u < 8; u++) z += (float)kk[u];
        }
        Z[((size_t)c * BHg + bh) * 64 + d] = z;
    }
}

// ---------------------------------------------------------------------------
// Phase B: exclusive prefix over chunks; register scan, loads all in flight.
// ---------------------------------------------------------------------------
__global__ __launch_bounds__(256) void attn_prefix(
    u16* __restrict__ S, float* __restrict__ Z, int BHg)
{
    int gid = blockIdx.x * 256 + threadIdx.x;   // < BHg*4096
    int bh = gid >> 12, e = gid & 4095;
    size_t stride = (size_t)BHg * 4096;
    size_t base = (size_t)bh * 4096 + e;
    float v[NCHUNK];
    #pragma unroll
    for (int c = 0; c < NCHUNK; c++) v[c] = b2f(S[base + c * stride]);
    float run = 0.f;
    #pragma unroll
    for (int c = 0; c < NCHUNK; c++) {
        float t = v[c]; S[base + c * stride] = f2b(run); run += t;
    }
    if (gid < BHg * 64) {
        size_t zb = (size_t)gid;
        size_t zs = (size_t)BHg * 64;
        float zv[NCHUNK];
        #pragma unroll
        for (int c = 0; c < NCHUNK; c++) zv[c] = Z[zb + c * zs];
        float zr = 0.f;
        #pragma unroll
        for (int c = 0; c < NCHUNK; c++) {
            float t = zv[c]; Z[zb + c * zs] = zr; zr += t;
        }
    }
}

// ---------------------------------------------------------------------------
// Phase C (MFMA): P=QK^T masked; O=(P@V + Q@S')/den.
// Loader: uint4 global + uint4 row-major LDS; skewed Vt. Ps aliases Ks.
// ---------------------------------------------------------------------------
__global__ __launch_bounds__(256) void attn_intra(
    const u16* __restrict__ qkv, const u16* __restrict__ Sp,
    const float* __restrict__ Zp, u16* __restrict__ out, int BHg)
{
    __shared__ __align__(16) u16 Qs[64 * 72], Ks[64 * 72], Vt[64 * 72],
                                 Ssh[64 * 72];
    __shared__ float Zsh[64], den2sh[64], den1sh[64];
    u16* Ps = Ks;                              // Ks dead after P-mfma
    int bid = blockIdx.x;
    int bh = bid % BHg, c = bid / BHg;
    int bl = bh >> 3, hh = bh & 7;
    size_t sbase = ((size_t)c * BHg + bh) * 4096;
    {
        const int m  = threadIdx.x & 7;
        const int d0 = m * 8;
        #pragma unroll
        for (int p = 0; p < 2; p++) {
            const int t = p * 32 + (threadIdx.x >> 3);
            size_t rr = ((size_t)(bl * T_SEQ + c * 64 + t)) * 1536 + hh * 64 + d0;
            *(uint4*)&Qs[t * 72 + d0]  = *(const uint4*)&qkv[rr];
            *(uint4*)&Ks[t * 72 + d0]  = *(const uint4*)&qkv[rr + 512];
            *(uint4*)&Ssh[t * 72 + d0] = *(const uint4*)&Sp[sbase + t * 64 + d0];
            uint4 vv = *(const uint4*)&qkv[rr + 1024];
            const u16* vp = (const u16*)&vv;
            const int sk = (t + d0) & 63;
            u16* vb = &Vt[d0 * 72 + sk];
            #pragma unroll
            for (int s = 0; s < 8; s++) vb[s * 72] = vp[s];
        }
    }
    if (threadIdx.x < 64)
        Zsh[threadIdx.x] = Zp[((size_t)c * BHg + bh) * 64 + threadIdx.x];
    __syncthreads();

    if (threadIdx.x < 64) {
        float s = 0.f;
        #pragma unroll
        for (int d8 = 0; d8 < 64; d8 += 8) {
            bf16x8 qq = *(const bf16x8*)&Qs[threadIdx.x * 72 + d8];
            #pragma unroll
            for (int u = 0; u < 8; u++) s += (float)qq[u] * Zsh[d8 + u];
        }
        den2sh[threadIdx.x] = s;
    }

    int lane = threadIdx.x & 63;
    int w = threadIdx.x >> 6;
    int lrow = lane & 15, quad = lane >> 4;
    int i0 = w * 16;

    // P = Q @ K^T (row = i via reg)
    f32x4 accp[4] = {};
    #pragma unroll
    for (int k0 = 0; k0 < 64; k0 += 32) {
        bf16x8 af = *(const bf16x8*)&Qs[(i0 + lrow) * 72 + k0 + quad * 8];
        #pragma unroll
        for (int jt = 0; jt < 4; jt++) {
            bf16x8 bf = *(const bf16x8*)&Ks[(jt * 16 + lrow) * 72 + k0 + quad * 8];
            accp[jt] = __builtin_amdgcn_mfma_f32_16x16x32_bf16(af, bf, accp[jt], 0, 0, 0);
        }
    }
    __syncthreads();                           // all Ks reads done before Ps writes
    #pragma unroll
    for (int r = 0; r < 4; r++) {
        int row = i0 + quad * 4 + r;
        float d1 = 0.f;
        #pragma unroll
        for (int jt = 0; jt < 4; jt++) {
            int col = jt * 16 + lrow;
            float pv = (col <= row) ? accp[jt][r] : 0.f;
            d1 += pv;
            Ps[row * 72 + col] = f2b(pv);
        }
        #pragma unroll
        for (int off = 1; off < 16; off <<= 1)
            d1 += __shfl_xor(d1, off, 64);
        if (lrow == 0) den1sh[row] = d1;
    }
    __syncthreads();

    // O = Ps @ V + Q @ S'  (swapped: first operand = m side)
    f32x4 acco[4] = {};
    #pragma unroll
    for (int k0 = 0; k0 < 64; k0 += 32) {
        bf16x8 ps = *(const bf16x8*)&Ps[(i0 + lrow) * 72 + k0 + quad * 8];
        #pragma unroll
        for (int jt = 0; jt < 4; jt++) {
            const int rv = jt * 16 + lrow;
            bf16x8 vf = *(const bf16x8*)&Vt[rv * 72 + SKEW(rv, k0 + quad * 8)];
            acco[jt] = __builtin_amdgcn_mfma_f32_16x16x32_bf16(vf, ps, acco[jt], 0, 0, 0);
        }
    }
    #pragma unroll
    for (int k0 = 0; k0 < 64; k0 += 32) {
        bf16x8 qf = *(const bf16x8*)&Qs[(i0 + lrow) * 72 + k0 + quad * 8];
        #pragma unroll
        for (int jt = 0; jt < 4; jt++) {
            bf16x8 sf = *(const bf16x8*)&Ssh[(jt * 16 + lrow) * 72 + k0 + quad * 8];
            acco[jt] = __builtin_amdgcn_mfma_f32_16x16x32_bf16(sf, qf, acco[jt], 0, 0, 0);
        }
    }
    const int i = i0 + lrow;
    const float inv = 1.f / (den1sh[i] + den2sh[i] + 1e-6f);
    size_t orow = ((size_t)(bl * T_SEQ + c * 64 + i)) * 512 + hh * 64;
    #pragma unroll
    for (int jt = 0; jt < 4; jt++) {
        const int m0 = jt * 16 + quad * 4;
        union { u16 q[4]; uint2 u; } pk;
        #pragma unroll
        for (int r = 0; r < 4; r++) pk.q[r] = f2b(acco[jt][r] * inv);
        *(uint2*)&out[orow + m0] = pk.u;
    }
}

// ---------------------------------------------------------------------------
// LayerNorm (single input stream; residual pre-added in GEMM epilogue).
// ---------------------------------------------------------------------------
__global__ __launch_bounds__(256) void ln_kernel(
    const u16* __restrict__ s_in,
    const float* __restrict__ g, const float* __restrict__ be, u16* __restrict__ out)
{
    int row = blockIdx.x * 4 + (threadIdx.x >> 6);
    int lane = threadIdx.x & 63;
    size_t base = (size_t)row * 512 + lane * 8;
    uint4 hv = *(const uint4*)&s_in[base];
    const u16* hp = (const u16*)&hv;
    float x[8]; float s = 0.f;
    #pragma unroll
    for (int i = 0; i < 8; i++) { x[i] = b2f(hp[i]); s += x[i]; }
    #pragma unroll
    for (int off = 32; off > 0; off >>= 1) s += __shfl_xor(s, off, 64);
    float m = s * (1.f / 512.f);
    float vs = 0.f;
    #pragma unroll
    for (int i = 0; i < 8; i++) { float t = x[i] - m; vs += t * t; }
    #pragma unroll
    for (int off = 32; off > 0; off >>= 1) vs += __shfl_xor(vs, off, 64);
    float rstd = rsqrtf(vs * (1.f / 512.f) + 1e-5f);
    union { u16 u[8]; uint4 v; } o;
    #pragma unroll
    for (int i = 0; i < 8; i++)
        o.u[i] = f2b((x[i] - m) * rstd * g[lane * 8 + i] + be[lane * 8 + i]);
    *(uint4*)&out[base] = o.v;
}

// ---------------------------------------------------------------------------
extern "C" void kernel_launch(void* const* d_in, const int* in_sizes, int n_in,
                              void* d_out, int out_size, void* d_ws, size_t ws_size,
                              hipStream_t stream)
{
    const int*   x  = (const int*)d_in[0];
    const float* E  = (const float*)d_in[1];
    const float* Wq = (const float*)d_in[2];
    const float* bq = (const float*)d_in[3];
    const float* Wk = (const float*)d_in[4];
    const float* bk = (const float*)d_in[5];
    const float* Wv = (const float*)d_in[6];
    const float* bv = (const float*)d_in[7];
    const float* Wo = (const float*)d_in[8];
    const float* bo = (const float*)d_in[9];
    const float* g1 = (const float*)d_in[10];
    const float* be1= (const float*)d_in[11];
    const float* W1 = (const float*)d_in[12];
    const float* b1 = (const float*)d_in[13];
    const float* W2 = (const float*)d_in[14];
    const float* b2 = (const float*)d_in[15];
    const float* g2 = (const float*)d_in[16];
    const float* be2= (const float*)d_in[17];
    const float* Wp = (const float*)d_in[18];
    const float* bp = (const float*)d_in[19];

    // --- fixed region: bf16 transposed weights + PE table + fp32 qkv bias ---
    char* p = (char*)d_ws;
    u16* qkvT = (u16*)p; p += (size_t)2 * 1536 * 512 * 2;
    u16* woT  = (u16*)p; p += (size_t)2 * 512 * 512 * 2;
    u16* w1T  = (u16*)p; p += (size_t)2 * 2048 * 512 * 2;
    u16* w2T  = (u16*)p; p += (size_t)2 * 512 * 2048 * 2;
    u16* wpT  = (u16*)p; p += (size_t)64 * 512 * 2;
    u16* pe   = (u16*)p; p += (size_t)T_SEQ * 256 * 2;     // 1 MiB
    float* bqkv = (float*)p; p += (size_t)16384;
    size_t fixed = (size_t)(p - (char*)d_ws);

    // --- adaptive batch group: Bg * 12.65 MiB ---
    const size_t perB = 12648448ULL;
    int Bg = 32;
    while (Bg > 1 && fixed + (size_t)Bg * perB > ws_size) Bg >>= 1;
    const int rows = Bg * T_SEQ;
    const int BHg = Bg * NHEADS;
    const int nbm = rows / 256;               // 256-row tiles (multiple of 8)

    u16* h      = (u16*)p; p += (size_t)rows * 512 * 2;
    u16* qkvBig = (u16*)p; p += (size_t)rows * 2048 * 2;
    u16* am     = (u16*)p; p += (size_t)rows * 512 * 2;
    float* Z    = (float*)p; p += (size_t)BHg * NCHUNK * 64 * 4;
    u16* qkv = qkvBig;                        // rows x 1536 during attention
    u16* Sb  = qkvBig + (size_t)rows * 1536;  // bf16 S' tail
    u16* ff1 = qkvBig;                        // rows x 2048 during FF
    u16* o_  = qkvBig;                        // rows x 512 Wo output (h+attn)

    dim3 blk(256);
    dim3 blk8(512);

    // one-shot preprocessing
    prep_kernel<<<8236, blk, 0, stream>>>(
        Wq, Wk, Wv, Wo, W1, W2, Wp, bq, bk, bv,
        qkvT, woT, w1T, w2T, wpT, pe, bqkv);

    for (int b0 = 0; b0 < BATCH; b0 += Bg) {
        embed_kernel<<<rows / 4, blk, 0, stream>>>(x, E, pe, h, b0);

        for (int l = 0; l < 2; l++) {
            gemm_p8<2, false><<<dim3(nbm * 6), blk8, 0, stream>>>(
                h, qkvT + (size_t)l * 786432, bqkv + l * 1536, nullptr, qkv,
                rows, 1536, 512, 1024, 6, 8);
            attn_chunk_sums<<<NCHUNK * BHg, blk, 0, stream>>>(qkv, Sb, Z, BHg);
            attn_prefix<<<BHg * 16, blk, 0, stream>>>(Sb, Z, BHg);
            attn_intra<<<NCHUNK * BHg, blk, 0, stream>>>(qkv, Sb, Z, am, BHg);
            gemm_p8<0, true><<<dim3(nbm * 2), blk8, 0, stream>>>(
                am, woT + (size_t)l * 262144, bo + l * 512, h, o_,
                rows, 512, 512, 0, 2, 8);
            ln_kernel<<<rows / 4, blk, 0, stream>>>(o_, g1 + l * 512, be1 + l * 512, h);
            gemm_p8<1, false><<<dim3(nbm * 8), blk8, 0, stream>>>(
                h, w1T + (size_t)l * 1048576, b1 + l * 2048, nullptr, ff1,
                rows, 2048, 512, 0, 8, 8);
            gemm_p8<0, true><<<dim3(nbm * 2), blk8, 0, stream>>>(
                ff1, w2T + (size_t)l * 1048576, b2 + l * 512, h, am,
                rows, 512, 2048, 0, 2, 8);
            ln_kernel<<<rows / 4, blk, 0, stream>>>(am, g2 + l * 512, be2 + l * 512, h);
        }

        gemm_sm<64, 64, 2, 2><<<dim3(1, rows / 64), blk, 0, stream>>>(
            h, wpT, bp, (float*)d_out + (size_t)b0 * T_SEQ * 64, rows, 64, 512);
    }

    (void)in_sizes; (void)n_in; (void)out_size; (void)ws_size;
}

// Round 12
// 1472.566 us; speedup vs baseline: 9.7414x; 9.7414x over previous
//
#include <hip/hip_runtime.h>

// ---------------------------------------------------------------------------
// SequencePredictorRecurrentTransformer on MI355X (gfx950)
//
// I/O: fp32 (x int32). Internal: bf16 storage, fp32 accumulation.
// Layout [b][t][d] bt-major. Batch groups of Bg sized to ws_size.
//
// Round-24: REVERT to round-22 (best verified: 1501.2us). Round-23's BK=32
// occupancy experiment exploded FETCH 49MB->2.1GB (2x resident blocks
// pushed per-XCD working set past the private 4MiB L2 -> every K-iter
// re-fetched from HBM) and tripled bank conflicts (4-wide granule XOR
// covers only 16 banks). GEMM is hereby FROZEN at this structure:
// schedule-merge/addr-hoist/de-pin/occupancy levers all explored;
// 256^2 tile, BK=64, GM-grouped order, de-pinned 2-phase counted-vmcnt
// dbuf is the source-level local optimum (~29% MfmaUtil, 49MB fetch).
// ---------------------------------------------------------------------------

typedef unsigned short u16;
typedef __bf16 bf16x8 __attribute__((ext_vector_type(8)));
typedef float f32x4 __attribute__((ext_vector_type(4)));
typedef float f32x16 __attribute__((ext_vector_type(16)));

#define T_SEQ 2048
#define BATCH 32
#define NHEADS 8
#define CT 64
#define NCHUNK 32             // T/CT

// skewed column offset for transposed LDS arrays (row r, t-index k)
#define SKEW(r, k) ((((k) + (((r) >> 3) << 3))) & 63)

__device__ __forceinline__ float b2f(u16 u) {
    union { unsigned int i; float f; } v; v.i = ((unsigned int)u) << 16; return v.f;
}
__device__ __forceinline__ u16 f2b(float f) {
    union { __bf16 b; u16 u; } v; v.b = (__bf16)f; return v.u;   // HW cvt, RNE
}

__device__ __forceinline__ void gl_lds16(const u16* g, u16* l) {
    __builtin_amdgcn_global_load_lds(
        (const __attribute__((address_space(1))) void*)g,
        (__attribute__((address_space(3))) void*)l,
        16, 0, 0);
}

// compiler-only memory fence (no hardware wait)
#define CFENCE() asm volatile("" ::: "memory")

// ---------------------------------------------------------------------------
// 256^2 2-phase GEMM: C[M,N] = act(A@BT^T + bias [+ R]), bf16 in/out.
// M,N multiples of 256; K multiple of 64, K>=128. grid = (M/256)*nbn,
// nbn = N/256, M/256 a multiple of GM. ACT: 0=none, 1=relu, 2=phi(elu+1)
// where col < act_split. Block order: GM bm-tiles per group, bn sweep.
// ---------------------------------------------------------------------------
template<int ACT, bool RES>
__global__ __launch_bounds__(512, 2) void gemm_p8(
    const u16* __restrict__ A, const u16* __restrict__ BT,
    const float* __restrict__ bias, const u16* __restrict__ R,
    u16* __restrict__ C,
    int M, int N, int K, int act_split, int nbn, int GM)
{
    __shared__ __align__(16) u16 AsS[2][256 * 64];
    __shared__ __align__(16) u16 BsS[2][256 * 64];

    // grouped ordering (gemm_mx-verified): GM bm-tiles per group, bn sweep
    const int bid = blockIdx.x;
    const int gsz = GM * nbn;
    const int grp = bid / gsz, rm = bid % gsz;
    const int bm = (grp * GM + rm % GM) * 256;
    const int bn = (rm / GM) * 256;
    if (bm >= M || bn >= N) return;           // guard (block-uniform)

    const int tid = threadIdx.x;
    const int lane = tid & 63;
    const int w  = tid >> 6;      // 0..7
    const int wr = w >> 2;        // 0..1 : M half (128 rows)
    const int wc = w & 3;         // 0..3 : N quarter (64 cols)
    const int l32 = lane & 31;
    const int kh  = lane >> 5;    // k-half selector for 32x32x16
    const int sr = lane >> 3;     // staging: row within 8-row chunk
    const int sg = lane & 7;      // staging: granule slot in row
    const int gs = sg ^ sr;       // source granule (r&7 == sr for all regions)

    const int NT = K >> 6;        // K-tiles of 64

    // --- hoisted per-thread global staging pointers ---
    const u16* pA[4]; const u16* pB[4];
    #pragma unroll
    for (int q = 0; q < 4; q++) {
        pA[q] = A  + (size_t)(bm + q * 64 + w * 8 + sr) * K + gs * 8;
        pB[q] = BT + (size_t)(bn + q * 64 + w * 8 + sr) * K + gs * 8;
    }

    // --- hoisted LDS read byte-offsets ---
    int offA[2][2][4], offB[2][4];
    #pragma unroll
    for (int h = 0; h < 2; h++)
        #pragma unroll
        for (int mf = 0; mf < 2; mf++) {
            const int r = wr * 128 + h * 64 + mf * 32 + l32;
            #pragma unroll
            for (int ks = 0; ks < 4; ks++)
                offA[h][mf][ks] = r * 128 + (((ks * 2 + kh) ^ (r & 7)) * 16);
        }
    #pragma unroll
    for (int jb = 0; jb < 2; jb++) {
        const int rb = wc * 64 + jb * 32 + l32;
        #pragma unroll
        for (int ks = 0; ks < 4; ks++)
            offB[jb][ks] = rb * 128 + (((ks * 2 + kh) ^ (rb & 7)) * 16);
    }

    f32x16 acc[4][2] = {};

    // stage 64 rows of region q at k-offset k0 (elements)
    auto stage = [&](u16* lds, const u16* p, int q, int k0) {
        gl_lds16(p + k0, lds + q * 4096 + w * 512);
    };

    // ---- prologue: tile 0 full (8), tile 1 A-q0 + B (6) ----
    #pragma unroll
    for (int q = 0; q < 4; q++) stage(AsS[0], pA[q], q, 0);
    #pragma unroll
    for (int q = 0; q < 4; q++) stage(BsS[0], pB[q], q, 0);
    stage(AsS[1], pA[0], 0, 64);
    stage(AsS[1], pA[2], 2, 64);
    #pragma unroll
    for (int q = 0; q < 4; q++) stage(BsS[1], pB[q], q, 64);
    asm volatile("s_waitcnt vmcnt(6)" ::: "memory");   // tile 0 landed
    __builtin_amdgcn_s_barrier();

    bf16x8 af[2][4], b0[4], b1[4];

    for (int t = 0; t < NT; ++t) {
        u16* As_ = AsS[t & 1];
        u16* Bs_ = BsS[t & 1];
        u16* An1 = AsS[(t + 1) & 1];          // other buffer
        const int k1 = (t + 1) << 6;
        const int k2 = (t + 2) << 6;
        const bool pf1 = (t + 1) < NT;
        const bool pf2 = (t + 2) < NT;

        // ===== phase A: read A-q0 + B(b0,b1); stage A-q1(t+1) -> other buf
        #pragma unroll
        for (int mf = 0; mf < 2; mf++)
            #pragma unroll
            for (int ks = 0; ks < 4; ks++)
                af[mf][ks] = *(const bf16x8*)((const char*)As_ + offA[0][mf][ks]);
        #pragma unroll
        for (int ks = 0; ks < 4; ks++) {
            b0[ks] = *(const bf16x8*)((const char*)Bs_ + offB[0][ks]);
            b1[ks] = *(const bf16x8*)((const char*)Bs_ + offB[1][ks]);
        }
        if (pf1) { stage(An1, pA[1], 1, k1); stage(An1, pA[3], 3, k1); }
        CFENCE();
        __builtin_amdgcn_s_barrier();
        CFENCE();
        // compiler schedules fine-grained lgkmcnt between reads and MFMAs
        #pragma unroll
        for (int ks = 0; ks < 4; ks++)
            #pragma unroll
            for (int mf = 0; mf < 2; mf++) {
                acc[mf][0] = __builtin_amdgcn_mfma_f32_32x32x16_bf16(
                    af[mf][ks], b0[ks], acc[mf][0], 0, 0, 0);
                acc[mf][1] = __builtin_amdgcn_mfma_f32_32x32x16_bf16(
                    af[mf][ks], b1[ks], acc[mf][1], 0, 0, 0);
            }
        CFENCE();
        __builtin_amdgcn_s_barrier();
        CFENCE();

        // ===== phase B: read A-q1; stage A-q0(t+2)+B(t+2) -> this buf =====
        #pragma unroll
        for (int mf = 0; mf < 2; mf++)
            #pragma unroll
            for (int ks = 0; ks < 4; ks++)
                af[mf][ks] = *(const bf16x8*)((const char*)As_ + offA[1][mf][ks]);
        if (pf2) {
            stage(As_, pA[0], 0, k2); stage(As_, pA[2], 2, k2);
            stage(Bs_, pB[0], 0, k2); stage(Bs_, pB[1], 1, k2);
            stage(Bs_, pB[2], 2, k2); stage(Bs_, pB[3], 3, k2);
        }
        CFENCE();
        __builtin_amdgcn_s_barrier();
        CFENCE();
        #pragma unroll
        for (int ks = 0; ks < 4; ks++)
            #pragma unroll
            for (int mf = 0; mf < 2; mf++) {
                acc[2 + mf][0] = __builtin_amdgcn_mfma_f32_32x32x16_bf16(
                    af[mf][ks], b0[ks], acc[2 + mf][0], 0, 0, 0);
                acc[2 + mf][1] = __builtin_amdgcn_mfma_f32_32x32x16_bf16(
                    af[mf][ks], b1[ks], acc[2 + mf][1], 0, 0, 0);
            }
        // retire tile t+1's 8 loads (keep phB(t)'s 6 for t+2 in flight)
        if (pf2) asm volatile("s_waitcnt vmcnt(6)" ::: "memory");
        else     asm volatile("s_waitcnt vmcnt(0)" ::: "memory");
        __builtin_amdgcn_s_barrier();
        CFENCE();
    }

    // Epilogue. D (m74/m101): col = lane&31, row = (reg&3)+8*(reg>>2)+4*kh.
    #pragma unroll
    for (int i = 0; i < 4; i++) {
        const int row0 = bm + wr * 128 + i * 32 + 4 * kh;
        #pragma unroll
        for (int j = 0; j < 2; j++) {
            const int col = bn + wc * 64 + j * 32 + l32;
            const float bb = bias[col];
            const bool phi = (ACT == 2) && (col < act_split);
            #pragma unroll
            for (int reg = 0; reg < 16; reg++) {
                const int m = row0 + (reg & 3) + 8 * (reg >> 2);
                float v = acc[i][j][reg] + bb;
                if (RES) v += b2f(R[(size_t)m * N + col]);
                if (ACT == 1) v = fmaxf(v, 0.f);
                if (ACT == 2) { if (phi) v = (v > 0.f) ? (v + 1.f) : __expf(v); }
                C[(size_t)m * N + col] = f2b(v);
            }
        }
    }
}

// ---------------------------------------------------------------------------
// Small-N GEMM (final projection, N=64): fp32 out, swapped epilogue (16B st).
// ---------------------------------------------------------------------------
template<int BM, int BN, int WM, int WN>
__global__ __launch_bounds__(WM*WN*64) void gemm_sm(
    const u16* __restrict__ A, const u16* __restrict__ BT,
    const float* __restrict__ bias, float* __restrict__ C,
    int M, int N, int K)
{
    constexpr int BK = 32;
    constexpr int LDT = BK + 8;
    constexpr int NTHR = WM * WN * 64;
    __shared__ __align__(16) u16 As[BM * LDT];
    __shared__ __align__(16) u16 Bs[BN * LDT];

    const int tid = threadIdx.x;
    const int bm = blockIdx.y * BM;
    const int bn = blockIdx.x * BN;
    const int lane = tid & 63;
    const int wid = tid >> 6;
    const int wrow = (wid / WN) * (BM / WM);
    const int wcol = (wid % WN) * (BN / WN);
    constexpr int FM = BM / WM / 16;
    constexpr int FN = BN / WN / 16;
    const int lrow = lane & 15;
    const int lk = (lane >> 4) * 8;

    f32x4 acc[FM][FN] = {};

    for (int k0 = 0; k0 < K; k0 += BK) {
        #pragma unroll
        for (int g0 = 0; g0 < BM * 4; g0 += NTHR) {
            int g = g0 + tid;
            int row = g >> 2, kk = (g & 3) * 8;
            *(uint4*)&As[row * LDT + kk] =
                *(const uint4*)&A[(size_t)(bm + row) * K + k0 + kk];
        }
        #pragma unroll
        for (int g0 = 0; g0 < BN * 4; g0 += NTHR) {
            int g = g0 + tid;
            int row = g >> 2, kk = (g & 3) * 8;
            *(uint4*)&Bs[row * LDT + kk] =
                *(const uint4*)&BT[(size_t)(bn + row) * K + k0 + kk];
        }
        __syncthreads();
        bf16x8 af[FM], bfv[FN];
        #pragma unroll
        for (int i = 0; i < FM; i++)
            af[i] = *(const bf16x8*)&As[(wrow + i * 16 + lrow) * LDT + lk];
        #pragma unroll
        for (int j = 0; j < FN; j++)
            bfv[j] = *(const bf16x8*)&Bs[(wcol + j * 16 + lrow) * LDT + lk];
        #pragma unroll
        for (int i = 0; i < FM; i++)
            #pragma unroll
            for (int j = 0; j < FN; j++)
                acc[i][j] = __builtin_amdgcn_mfma_f32_16x16x32_bf16(
                    bfv[j], af[i], acc[i][j], 0, 0, 0);   // swapped
        __syncthreads();
    }

    #pragma unroll
    for (int i = 0; i < FM; i++) {
        const int row = bm + wrow + i * 16 + lrow;
        #pragma unroll
        for (int j = 0; j < FN; j++) {
            const int col0 = bn + wcol + j * 16 + (lane >> 4) * 4;
            const float4 bb = *(const float4*)&bias[col0];
            float4 o = { acc[i][j][0] + bb.x, acc[i][j][1] + bb.y,
                         acc[i][j][2] + bb.z, acc[i][j][3] + bb.w };
            *(float4*)&C[(size_t)row * N + col0] = o;
        }
    }
}

// ---------------------------------------------------------------------------
// Mega-preprocess: ALL weight transposes (fp32->bf16) + PE table + qkv bias
// concat in ONE dispatch. Block ranges (block-uniform branches).
// ---------------------------------------------------------------------------
__global__ __launch_bounds__(256) void prep_kernel(
    const float* __restrict__ Wq, const float* __restrict__ Wk,
    const float* __restrict__ Wv, const float* __restrict__ Wo,
    const float* __restrict__ W1, const float* __restrict__ W2,
    const float* __restrict__ Wp,
    const float* __restrict__ bq, const float* __restrict__ bk,
    const float* __restrict__ bv,
    u16* __restrict__ qkvT, u16* __restrict__ woT, u16* __restrict__ w1T,
    u16* __restrict__ w2T, u16* __restrict__ wpT, u16* __restrict__ pe,
    float* __restrict__ bqkv)
{
    __shared__ float tile[32][33];
    const int bid = blockIdx.x;
    const float* src; u16* dst; int K, N, bx, by;

    if (bid < 1536) {
        int l = bid / 768, r = bid % 768, m = r >> 8, t = r & 255;
        const float* s3[3] = { Wq, Wk, Wv };            // m block-uniform
        src = s3[m] + (size_t)l * 262144;
        dst = qkvT + (size_t)l * 786432 + (size_t)m * 262144;
        K = 512; N = 512; bx = t & 15; by = t >> 4;
    } else if (bid < 2048) {
        int r = bid - 1536, l = r >> 8, t = r & 255;
        src = Wo + (size_t)l * 262144; dst = woT + (size_t)l * 262144;
        K = 512; N = 512; bx = t & 15; by = t >> 4;
    } else if (bid < 4096) {
        int r = bid - 2048, l = r >> 10, t = r & 1023;
        src = W1 + (size_t)l * 1048576; dst = w1T + (size_t)l * 1048576;
        K = 512; N = 2048; bx = t & 63; by = t >> 6;
    } else if (bid < 6144) {
        int r = bid - 4096, l = r >> 10, t = r & 1023;
        src = W2 + (size_t)l * 1048576; dst = w2T + (size_t)l * 1048576;
        K = 2048; N = 512; bx = t & 15; by = t >> 4;
    } else if (bid < 6176) {
        int t = bid - 6144;
        src = Wp; dst = wpT; K = 512; N = 64; bx = t & 1; by = t >> 1;
    } else if (bid < 8224) {
        int id = (bid - 6176) * 256 + threadIdx.x;      // < 2048*256
        int t = id >> 8, j = id & 255;
        int i = j >> 1;
        float div = expf(-(float)(2 * i) * (9.210340371976184f / 256.f));
        float arg = (float)t * div;
        pe[id] = f2b((j & 1) ? cosf(arg) : sinf(arg));
        return;
    } else {
        int id = (bid - 8224) * 256 + threadIdx.x;
        if (id < 3072) {
            int l = id / 1536, i2 = id % 1536;
            float v = (i2 < 512) ? bq[l * 512 + i2]
                    : (i2 < 1024) ? bk[l * 512 + i2 - 512]
                                  : bv[l * 512 + i2 - 1024];
            bqkv[id] = v;
        }
        return;
    }

    // 32x32 transpose tile: dst[N][K] = bf16(src[K][N])
    int tx = threadIdx.x & 31, ty = threadIdx.x >> 5;
    #pragma unroll
    for (int yy = 0; yy < 4; yy++) {
        int k = by * 32 + ty + yy * 8;
        tile[ty + yy * 8][tx] = src[(size_t)k * N + bx * 32 + tx];
    }
    __syncthreads();
    #pragma unroll
    for (int yy = 0; yy < 4; yy++) {
        int n = bx * 32 + ty + yy * 8;
        dst[(size_t)n * K + by * 32 + tx] = f2b(tile[tx][ty + yy * 8]);
    }
}

// ---------------------------------------------------------------------------
// Embedding (bt-major): gather from E and the PE table, 8 elems/thread.
// Grid = rows/4 blocks of 256 threads (2048 u16 per block).
// ---------------------------------------------------------------------------
__global__ __launch_bounds__(256) void embed_kernel(
    const int* __restrict__ x, const float* __restrict__ E,
    const u16* __restrict__ pe, u16* __restrict__ h, int b0)
{
    int idx = blockIdx.x * 256 + threadIdx.x;   // 8-elem granule id
    int e8 = idx * 8;
    int r = e8 >> 9;          // global row
    int c = e8 & 511;         // col base (multiple of 8)
    int t = r & (T_SEQ - 1);
    int b = b0 + (r >> 11);
    union { u16 u[8]; uint4 v; } o;
    if (c < 256) {
        const float* Ep = &E[(size_t)x[t * BATCH + b] * 256 + c];
        #pragma unroll
        for (int i = 0; i < 8; i++) o.u[i] = f2b(Ep[i]);
    } else {
        o.v = *(const uint4*)&pe[t * 256 + (c - 256)];
    }
    *(uint4*)&h[e8] = o.v;
}

// ---------------------------------------------------------------------------
// Phase A (MFMA): S'_c[m][d] = sum_t V[t][m]*K[t][d] -> bf16; Z_c[d]=sum K.
// Loader: uint4 global; skewed transposed LDS stores (static reg indexing).
// ---------------------------------------------------------------------------
__global__ __launch_bounds__(256) void attn_chunk_sums(
    const u16* __restrict__ qkv, u16* __restrict__ S, float* __restrict__ Z,
    int BHg)
{
    __shared__ __align__(16) u16 Kt[64 * 72], Vt[64 * 72];   // skewed [d][t]
    int bid = blockIdx.x;
    int bh = bid % BHg, c = bid / BHg;
    int bl = bh >> 3, hh = bh & 7;
    {
        const int m  = threadIdx.x & 7;
        const int d0 = m * 8;
        #pragma unroll
        for (int p = 0; p < 2; p++) {
            const int t = p * 32 + (threadIdx.x >> 3);
            size_t rr = ((size_t)(bl * T_SEQ + c * 64 + t)) * 1536 + hh * 64 + d0;
            uint4 kv = *(const uint4*)&qkv[rr + 512];
            uint4 vv = *(const uint4*)&qkv[rr + 1024];
            const u16* kp = (const u16*)&kv;
            const u16* vp = (const u16*)&vv;
            const int sk = (t + d0) & 63;         // skew col for rows d0..d0+7
            u16* kb = &Kt[d0 * 72 + sk];
            u16* vb = &Vt[d0 * 72 + sk];
            #pragma unroll
            for (int s = 0; s < 8; s++) { kb[s * 72] = kp[s]; vb[s * 72] = vp[s]; }
        }
    }
    __syncthreads();
    int lane = threadIdx.x & 63;
    int w = threadIdx.x >> 6;
    int lrow = lane & 15, quad = lane >> 4;
    int m0 = w * 16;
    f32x4 acc[4] = {};
    #pragma unroll
    for (int k0 = 0; k0 < 64; k0 += 32) {
        const int ra = m0 + lrow;
        bf16x8 af = *(const bf16x8*)&Vt[ra * 72 + SKEW(ra, k0 + quad * 8)];
        #pragma unroll
        for (int jt = 0; jt < 4; jt++) {
            const int rb = jt * 16 + lrow;
            bf16x8 bf = *(const bf16x8*)&Kt[rb * 72 + SKEW(rb, k0 + quad * 8)];
            acc[jt] = __builtin_amdgcn_mfma_f32_16x16x32_bf16(bf, af, acc[jt], 0, 0, 0);
        }
    }
    size_t base = ((size_t)c * BHg + bh) * 4096;
    const int m = m0 + lrow;
    #pragma unroll
    for (int jt = 0; jt < 4; jt++) {
        const int d0 = jt * 16 + quad * 4;
        union { u16 q[4]; uint2 u; } pk;
        #pragma unroll
        for (int r = 0; r < 4; r++) pk.q[r] = f2b(acc[jt][r]);
        *(uint2*)&S[base + m * 64 + d0] = pk.u;
    }
    if (threadIdx.x < 64) {
        const int d = threadIdx.x;
        float z = 0.f;
        #pragma unroll
        for (int t8 = 0; t8 < 64; t8 += 8) {
            bf16x8 kk = *(const bf16x8*)&Kt[d * 72 + SKEW(d, t8)];
            #pragma unroll
            for (int u = 0; u < 8; u++) z += (float)kk[u];
        }
        Z[((size_t)c * BHg + bh) * 64 + d] = z;
    }
}

// ---------------------------------------------------------------------------
// Phase B: exclusive prefix over chunks; register scan, loads all in flight.
// ---------------------------------------------------------------------------
__global__ __launch_bounds__(256) void attn_prefix(
    u16* __restrict__ S, float* __restrict__ Z, int BHg)
{
    int gid = blockIdx.x * 256 + threadIdx.x;   // < BHg*4096
    int bh = gid >> 12, e = gid & 4095;
    size_t stride = (size_t)BHg * 4096;
    size_t base = (size_t)bh * 4096 + e;
    float v[NCHUNK];
    #pragma unroll
    for (int c = 0; c < NCHUNK; c++) v[c] = b2f(S[base + c * stride]);
    float run = 0.f;
    #pragma unroll
    for (int c = 0; c < NCHUNK; c++) {
        float t = v[c]; S[base + c * stride] = f2b(run); run += t;
    }
    if (gid < BHg * 64) {
        size_t zb = (size_t)gid;
        size_t zs = (size_t)BHg * 64;
        float zv[NCHUNK];
        #pragma unroll
        for (int c = 0; c < NCHUNK; c++) zv[c] = Z[zb + c * zs];
        float zr = 0.f;
        #pragma unroll
        for (int c = 0; c < NCHUNK; c++) {
            float t = zv[c]; Z[zb + c * zs] = zr; zr += t;
        }
    }
}

// ---------------------------------------------------------------------------
// Phase C (MFMA): P=QK^T masked; O=(P@V + Q@S')/den.
// Loader: uint4 global + uint4 row-major LDS; skewed Vt. Ps aliases Ks.
// ---------------------------------------------------------------------------
__global__ __launch_bounds__(256) void attn_intra(
    const u16* __restrict__ qkv, const u16* __restrict__ Sp,
    const float* __restrict__ Zp, u16* __restrict__ out, int BHg)
{
    __shared__ __align__(16) u16 Qs[64 * 72], Ks[64 * 72], Vt[64 * 72],
                                 Ssh[64 * 72];
    __shared__ float Zsh[64], den2sh[64], den1sh[64];
    u16* Ps = Ks;                              // Ks dead after P-mfma
    int bid = blockIdx.x;
    int bh = bid % BHg, c = bid / BHg;
    int bl = bh >> 3, hh = bh & 7;
    size_t sbase = ((size_t)c * BHg + bh) * 4096;
    {
        const int m  = threadIdx.x & 7;
        const int d0 = m * 8;
        #pragma unroll
        for (int p = 0; p < 2; p++) {
            const int t = p * 32 + (threadIdx.x >> 3);
            size_t rr = ((size_t)(bl * T_SEQ + c * 64 + t)) * 1536 + hh * 64 + d0;
            *(uint4*)&Qs[t * 72 + d0]  = *(const uint4*)&qkv[rr];
            *(uint4*)&Ks[t * 72 + d0]  = *(const uint4*)&qkv[rr + 512];
            *(uint4*)&Ssh[t * 72 + d0] = *(const uint4*)&Sp[sbase + t * 64 + d0];
            uint4 vv = *(const uint4*)&qkv[rr + 1024];
            const u16* vp = (const u16*)&vv;
            const int sk = (t + d0) & 63;
            u16* vb = &Vt[d0 * 72 + sk];
            #pragma unroll
            for (int s = 0; s < 8; s++) vb[s * 72] = vp[s];
        }
    }
    if (threadIdx.x < 64)
        Zsh[threadIdx.x] = Zp[((size_t)c * BHg + bh) * 64 + threadIdx.x];
    __syncthreads();

    if (threadIdx.x < 64) {
        float s = 0.f;
        #pragma unroll
        for (int d8 = 0; d8 < 64; d8 += 8) {
            bf16x8 qq = *(const bf16x8*)&Qs[threadIdx.x * 72 + d8];
            #pragma unroll
            for (int u = 0; u < 8; u++) s += (float)qq[u] * Zsh[d8 + u];
        }
        den2sh[threadIdx.x] = s;
    }

    int lane = threadIdx.x & 63;
    int w = threadIdx.x >> 6;
    int lrow = lane & 15, quad = lane >> 4;
    int i0 = w * 16;

    // P = Q @ K^T (row = i via reg)
    f32x4 accp[4] = {};
    #pragma unroll
    for (int k0 = 0; k0 < 64; k0 += 32) {
        bf16x8 af = *(const bf16x8*)&Qs[(i0 + lrow) * 72 + k0 + quad * 8];
        #pragma unroll
        for (int jt = 0; jt < 4; jt++) {
            bf16x8 bf = *(const bf16x8*)&Ks[(jt * 16 + lrow) * 72 + k0 + quad * 8];
            accp[jt] = __builtin_amdgcn_mfma_f32_16x16x32_bf16(af, bf, accp[jt], 0, 0, 0);
        }
    }
    __syncthreads();                           // all Ks reads done before Ps writes
    #pragma unroll
    for (int r = 0; r < 4; r++) {
        int row = i0 + quad * 4 + r;
        float d1 = 0.f;
        #pragma unroll
        for (int jt = 0; jt < 4; jt++) {
            int col = jt * 16 + lrow;
            float pv = (col <= row) ? accp[jt][r] : 0.f;
            d1 += pv;
            Ps[row * 72 + col] = f2b(pv);
        }
        #pragma unroll
        for (int off = 1; off < 16; off <<= 1)
            d1 += __shfl_xor(d1, off, 64);
        if (lrow == 0) den1sh[row] = d1;
    }
    __syncthreads();

    // O = Ps @ V + Q @ S'  (swapped: first operand = m side)
    f32x4 acco[4] = {};
    #pragma unroll
    for (int k0 = 0; k0 < 64; k0 += 32) {
        bf16x8 ps = *(const bf16x8*)&Ps[(i0 + lrow) * 72 + k0 + quad * 8];
        #pragma unroll
        for (int jt = 0; jt < 4; jt++) {
            const int rv = jt * 16 + lrow;
            bf16x8 vf = *(const bf16x8*)&Vt[rv * 72 + SKEW(rv, k0 + quad * 8)];
            acco[jt] = __builtin_amdgcn_mfma_f32_16x16x32_bf16(vf, ps, acco[jt], 0, 0, 0);
        }
    }
    #pragma unroll
    for (int k0 = 0; k0 < 64; k0 += 32) {
        bf16x8 qf = *(const bf16x8*)&Qs[(i0 + lrow) * 72 + k0 + quad * 8];
        #pragma unroll
        for (int jt = 0; jt < 4; jt++) {
            bf16x8 sf = *(const bf16x8*)&Ssh[(jt * 16 + lrow) * 72 + k0 + quad * 8];
            acco[jt] = __builtin_amdgcn_mfma_f32_16x16x32_bf16(sf, qf, acco[jt], 0, 0, 0);
        }
    }
    const int i = i0 + lrow;
    const float inv = 1.f / (den1sh[i] + den2sh[i] + 1e-6f);
    size_t orow = ((size_t)(bl * T_SEQ + c * 64 + i)) * 512 + hh * 64;
    #pragma unroll
    for (int jt = 0; jt < 4; jt++) {
        const int m0 = jt * 16 + quad * 4;
        union { u16 q[4]; uint2 u; } pk;
        #pragma unroll
        for (int r = 0; r < 4; r++) pk.q[r] = f2b(acco[jt][r] * inv);
        *(uint2*)&out[orow + m0] = pk.u;
    }
}

// ---------------------------------------------------------------------------
// LayerNorm (single input stream; residual pre-added in GEMM epilogue).
// ---------------------------------------------------------------------------
__global__ __launch_bounds__(256) void ln_kernel(
    const u16* __restrict__ s_in,
    const float* __restrict__ g, const float* __restrict__ be, u16* __restrict__ out)
{
    int row = blockIdx.x * 4 + (threadIdx.x >> 6);
    int lane = threadIdx.x & 63;
    size_t base = (size_t)row * 512 + lane * 8;
    uint4 hv = *(const uint4*)&s_in[base];
    const u16* hp = (const u16*)&hv;
    float x[8]; float s = 0.f;
    #pragma unroll
    for (int i = 0; i < 8; i++) { x[i] = b2f(hp[i]); s += x[i]; }
    #pragma unroll
    for (int off = 32; off > 0; off >>= 1) s += __shfl_xor(s, off, 64);
    float m = s * (1.f / 512.f);
    float vs = 0.f;
    #pragma unroll
    for (int i = 0; i < 8; i++) { float t = x[i] - m; vs += t * t; }
    #pragma unroll
    for (int off = 32; off > 0; off >>= 1) vs += __shfl_xor(vs, off, 64);
    float rstd = rsqrtf(vs * (1.f / 512.f) + 1e-5f);
    union { u16 u[8]; uint4 v; } o;
    #pragma unroll
    for (int i = 0; i < 8; i++)
        o.u[i] = f2b((x[i] - m) * rstd * g[lane * 8 + i] + be[lane * 8 + i]);
    *(uint4*)&out[base] = o.v;
}

// ---------------------------------------------------------------------------
extern "C" void kernel_launch(void* const* d_in, const int* in_sizes, int n_in,
                              void* d_out, int out_size, void* d_ws, size_t ws_size,
                              hipStream_t stream)
{
    const int*   x  = (const int*)d_in[0];
    const float* E  = (const float*)d_in[1];
    const float* Wq = (const float*)d_in[2];
    const float* bq = (const float*)d_in[3];
    const float* Wk = (const float*)d_in[4];
    const float* bk = (const float*)d_in[5];
    const float* Wv = (const float*)d_in[6];
    const float* bv = (const float*)d_in[7];
    const float* Wo = (const float*)d_in[8];
    const float* bo = (const float*)d_in[9];
    const float* g1 = (const float*)d_in[10];
    const float* be1= (const float*)d_in[11];
    const float* W1 = (const float*)d_in[12];
    const float* b1 = (const float*)d_in[13];
    const float* W2 = (const float*)d_in[14];
    const float* b2 = (const float*)d_in[15];
    const float* g2 = (const float*)d_in[16];
    const float* be2= (const float*)d_in[17];
    const float* Wp = (const float*)d_in[18];
    const float* bp = (const float*)d_in[19];

    // --- fixed region: bf16 transposed weights + PE table + fp32 qkv bias ---
    char* p = (char*)d_ws;
    u16* qkvT = (u16*)p; p += (size_t)2 * 1536 * 512 * 2;
    u16* woT  = (u16*)p; p += (size_t)2 * 512 * 512 * 2;
    u16* w1T  = (u16*)p; p += (size_t)2 * 2048 * 512 * 2;
    u16* w2T  = (u16*)p; p += (size_t)2 * 512 * 2048 * 2;
    u16* wpT  = (u16*)p; p += (size_t)64 * 512 * 2;
    u16* pe   = (u16*)p; p += (size_t)T_SEQ * 256 * 2;     // 1 MiB
    float* bqkv = (float*)p; p += (size_t)16384;
    size_t fixed = (size_t)(p - (char*)d_ws);

    // --- adaptive batch group: Bg * 12.65 MiB ---
    const size_t perB = 12648448ULL;
    int Bg = 32;
    while (Bg > 1 && fixed + (size_t)Bg * perB > ws_size) Bg >>= 1;
    const int rows = Bg * T_SEQ;
    const int BHg = Bg * NHEADS;
    const int nbm = rows / 256;               // 256-row tiles (multiple of 8)

    u16* h      = (u16*)p; p += (size_t)rows * 512 * 2;
    u16* qkvBig = (u16*)p; p += (size_t)rows * 2048 * 2;
    u16* am     = (u16*)p; p += (size_t)rows * 512 * 2;
    float* Z    = (float*)p; p += (size_t)BHg * NCHUNK * 64 * 4;
    u16* qkv = qkvBig;                        // rows x 1536 during attention
    u16* Sb  = qkvBig + (size_t)rows * 1536;  // bf16 S' tail
    u16* ff1 = qkvBig;                        // rows x 2048 during FF
    u16* o_  = qkvBig;                        // rows x 512 Wo output (h+attn)

    dim3 blk(256);
    dim3 blk8(512);

    // one-shot preprocessing
    prep_kernel<<<8236, blk, 0, stream>>>(
        Wq, Wk, Wv, Wo, W1, W2, Wp, bq, bk, bv,
        qkvT, woT, w1T, w2T, wpT, pe, bqkv);

    for (int b0 = 0; b0 < BATCH; b0 += Bg) {
        embed_kernel<<<rows / 4, blk, 0, stream>>>(x, E, pe, h, b0);

        for (int l = 0; l < 2; l++) {
            gemm_p8<2, false><<<dim3(nbm * 6), blk8, 0, stream>>>(
                h, qkvT + (size_t)l * 786432, bqkv + l * 1536, nullptr, qkv,
                rows, 1536, 512, 1024, 6, 8);
            attn_chunk_sums<<<NCHUNK * BHg, blk, 0, stream>>>(qkv, Sb, Z, BHg);
            attn_prefix<<<BHg * 16, blk, 0, stream>>>(Sb, Z, BHg);
            attn_intra<<<NCHUNK * BHg, blk, 0, stream>>>(qkv, Sb, Z, am, BHg);
            gemm_p8<0, true><<<dim3(nbm * 2), blk8, 0, stream>>>(
                am, woT + (size_t)l * 262144, bo + l * 512, h, o_,
                rows, 512, 512, 0, 2, 8);
            ln_kernel<<<rows / 4, blk, 0, stream>>>(o_, g1 + l * 512, be1 + l * 512, h);
            gemm_p8<1, false><<<dim3(nbm * 8), blk8, 0, stream>>>(
                h, w1T + (size_t)l * 1048576, b1 + l * 2048, nullptr, ff1,
                rows, 2048, 512, 0, 8, 8);
            gemm_p8<0, true><<<dim3(nbm * 2), blk8, 0, stream>>>(
                ff1, w2T + (size_t)l * 1048576, b2 + l * 512, h, am,
                rows, 512, 2048, 0, 2, 8);
            ln_kernel<<<rows / 4, blk, 0, stream>>>(am, g2 + l * 512, be2 + l * 512, h);
        }

        gemm_sm<64, 64, 2, 2><<<dim3(1, rows / 64), blk, 0, stream>>>(
            h, wpT, bp, (float*)d_out + (size_t)b0 * T_SEQ * 64, rows, 64, 512);
    }

    (void)in_sizes; (void)n_in; (void)out_size; (void)ws_size;
}